// Round 1
// baseline (21447.871 us; speedup 1.0000x reference)
//
#include <hip/hip_runtime.h>
#include <hip/hip_bf16.h>

#define Bb 128
#define Tt 512
#define Dd 1024
#define Hh 1024
#define KD 2048
#define NZ 32
#define BK 64
#define NKI (KD / BK)

typedef __attribute__((ext_vector_type(4))) float f32x4;
typedef __attribute__((ext_vector_type(8))) short s16x8;

__device__ __forceinline__ unsigned short f2bf(float f) {
    union { float f; unsigned u; } v;
    v.f = f;
    unsigned r = v.u + 0x7fffu + ((v.u >> 16) & 1u);
    return (unsigned short)(r >> 16);
}

// One LSTM time step, fused: z = [x_t, h] @ W + b ; gates ; c,h update ; output.
// Grid: 256 blocks = 128 column-groups (g) x 2 batch-halves (mh).
// Block: M=64 rows, N=32 z-cols (= 8 h-cols x 4 gates), K=2048.
__global__ __launch_bounds__(256) void lstm_step(
    const float* __restrict__ X,            // [B][T][D] fp32
    const unsigned short* __restrict__ Wr,  // [4096][2048] bf16, row n = g*32+gate*8+jj
    const float* __restrict__ bF, const float* __restrict__ bI,
    const float* __restrict__ bO, const float* __restrict__ bC,
    const unsigned short* __restrict__ hin, // [B][H] bf16
    unsigned short* __restrict__ hout,      // [B][H] bf16
    float* __restrict__ cbuf,               // [B][H] fp32
    float* __restrict__ out,                // [B][T][H] fp32
    int t)
{
    __shared__ __align__(16) unsigned short Alds[2][64 * BK]; // [r][k] swizzled
    __shared__ __align__(16) unsigned short Blds[2][NZ * BK]; // [n][k] swizzled
    __shared__ float zlds[64 * 33];

    const int tid  = threadIdx.x;
    const int lane = tid & 63;
    const int w    = tid >> 6;           // wave 0..3 -> M-tile
    const int g    = blockIdx.x >> 1;    // column group 0..127
    const int mh   = blockIdx.x & 1;     // batch half

    f32x4 acc[2];
    acc[0] = 0.f; acc[1] = 0.f;

    // stage A tile [64 rows][64 k] bf16 (8KB). swizzle: dest chunk cp holds src chunk cp^(r&7)
    auto stageA = [&](int buf, int ki) {
        const int k0 = ki * BK;
#pragma unroll
        for (int i = 0; i < 2; ++i) {
            int slot = tid + 256 * i;      // 512 slots of 16B
            int r  = slot >> 3;
            int cp = slot & 7;
            int c  = cp ^ (r & 7);
            int k  = k0 + c * 8;
            s16x8 v;
            if (k < Dd) {
                const float* src = X + ((size_t)(mh * 64 + r) * Tt + t) * Dd + k;
                f32x4 a = *reinterpret_cast<const f32x4*>(src);
                f32x4 b = *reinterpret_cast<const f32x4*>(src + 4);
                v[0] = (short)f2bf(a[0]); v[1] = (short)f2bf(a[1]);
                v[2] = (short)f2bf(a[2]); v[3] = (short)f2bf(a[3]);
                v[4] = (short)f2bf(b[0]); v[5] = (short)f2bf(b[1]);
                v[6] = (short)f2bf(b[2]); v[7] = (short)f2bf(b[3]);
            } else {
                v = *reinterpret_cast<const s16x8*>(hin + (size_t)(mh * 64 + r) * Hh + (k - Dd));
            }
            *reinterpret_cast<s16x8*>(&Alds[buf][r * BK + cp * 8]) = v;
        }
    };

    // stage B tile [32 n][64 k] bf16 (4KB), from pre-transposed weight panel
    auto stageB = [&](int buf, int ki) {
        const int k0 = ki * BK;
        int n  = tid >> 3;
        int cp = tid & 7;
        int c  = cp ^ (n & 7);
        const unsigned short* src = Wr + (size_t)(g * NZ + n) * KD + k0 + c * 8;
        *reinterpret_cast<s16x8*>(&Blds[buf][n * BK + cp * 8]) =
            *reinterpret_cast<const s16x8*>(src);
    };

    auto compute = [&](int buf) {
#pragma unroll
        for (int ks = 0; ks < 2; ++ks) {
            int ra  = w * 16 + (lane & 15);
            int cha = (ks * 4 + (lane >> 4)) ^ (ra & 7);
            s16x8 afrag = *reinterpret_cast<const s16x8*>(&Alds[buf][ra * BK + cha * 8]);
#pragma unroll
            for (int nt = 0; nt < 2; ++nt) {
                int n   = nt * 16 + (lane & 15);
                int chb = (ks * 4 + (lane >> 4)) ^ (n & 7);
                s16x8 bfrag = *reinterpret_cast<const s16x8*>(&Blds[buf][n * BK + chb * 8]);
                acc[nt] = __builtin_amdgcn_mfma_f32_16x16x32_bf16(afrag, bfrag, acc[nt], 0, 0, 0);
            }
        }
    };

    stageA(0, 0);
    stageB(0, 0);
#pragma unroll 1
    for (int ki = 0; ki < NKI; ++ki) {
        __syncthreads();  // staging of buf[ki&1] visible; prev compute done
        if (ki + 1 < NKI) {
            stageA((ki + 1) & 1, ki + 1);
            stageB((ki + 1) & 1, ki + 1);
        }
        compute(ki & 1);
    }

    // dump z (acc) to LDS: D-layout col=lane&15, row=(lane>>4)*4+reg
    {
        int rbase = w * 16 + (lane >> 4) * 4;
#pragma unroll
        for (int nt = 0; nt < 2; ++nt) {
            int col = nt * 16 + (lane & 15);
#pragma unroll
            for (int r = 0; r < 4; ++r)
                zlds[(rbase + r) * 33 + col] = acc[nt][r];
        }
    }
    __syncthreads();

    // gates + state update + output (cols jj, 8+jj, 16+jj, 24+jj = f,i,o,g)
#pragma unroll
    for (int it = 0; it < 2; ++it) {
        int idx  = tid + it * 256;          // 512 items = 64 rows x 8 cols
        int row  = idx >> 3;
        int jj   = idx & 7;
        int j    = g * 8 + jj;
        int grow = mh * 64 + row;
        float zf = zlds[row * 33 + jj]      + bF[j];
        float zi = zlds[row * 33 + 8 + jj]  + bI[j];
        float zo = zlds[row * 33 + 16 + jj] + bO[j];
        float zc = zlds[row * 33 + 24 + jj] + bC[j];
        float fg = 1.f / (1.f + __expf(-zf));
        float ig = 1.f / (1.f + __expf(-zi));
        float og = 1.f / (1.f + __expf(-zo));
        float gg = tanhf(zc);
        float cold = cbuf[(size_t)grow * Hh + j];
        float cnew = fg * cold + ig * gg;
        cbuf[(size_t)grow * Hh + j] = cnew;
        float hn = og * tanhf(cnew);
        hout[(size_t)grow * Hh + j] = f2bf(hn);
        out[((size_t)grow * Tt + (Tt - 1 - t)) * Hh + j] = hn;  // reversed time order
    }
}

// One-time (per call) weight reorg: Wr[n][k] bf16 with n = g*32 + gate*8 + jj,
// source col = g*8 + jj of W_gate [2048][1024] fp32.
__global__ void conv_w(const float* __restrict__ Wf, const float* __restrict__ Wi,
                       const float* __restrict__ Wo, const float* __restrict__ Wc,
                       unsigned short* __restrict__ Wr) {
    int n = blockIdx.x;                 // 0..4095
    int g = n >> 5, rem = n & 31, gate = rem >> 3, jj = rem & 7;
    int col = g * 8 + jj;
    const float* Wg = (gate == 0) ? Wf : (gate == 1) ? Wi : (gate == 2) ? Wo : Wc;
#pragma unroll
    for (int i = 0; i < 8; ++i) {
        int k = threadIdx.x + i * 256;
        Wr[(size_t)n * KD + k] = f2bf(Wg[(size_t)k * Hh + col]);
    }
}

__global__ void init_state(unsigned short* __restrict__ h0, float* __restrict__ c0) {
    int i = blockIdx.x * 256 + threadIdx.x;
    if (i < Bb * Hh) { h0[i] = 0; c0[i] = 0.f; }
}

extern "C" void kernel_launch(void* const* d_in, const int* in_sizes, int n_in,
                              void* d_out, int out_size, void* d_ws, size_t ws_size,
                              hipStream_t stream) {
    (void)in_sizes; (void)n_in; (void)out_size; (void)ws_size;
    const float* X  = (const float*)d_in[0];
    const float* Wf = (const float*)d_in[1];
    const float* bF = (const float*)d_in[2];
    const float* Wi = (const float*)d_in[3];
    const float* bI = (const float*)d_in[4];
    const float* Wo = (const float*)d_in[5];
    const float* bO = (const float*)d_in[6];
    const float* Wc = (const float*)d_in[7];
    const float* bC = (const float*)d_in[8];
    float* out = (float*)d_out;

    char* ws = (char*)d_ws;
    unsigned short* Wr   = (unsigned short*)ws;                            // 16 MB
    unsigned short* hbuf = (unsigned short*)(ws + (size_t)4096 * KD * 2);  // 2 x 256 KB
    float*          cbuf = (float*)(ws + (size_t)4096 * KD * 2 + 2 * (size_t)Bb * Hh * 2);

    conv_w<<<4096, 256, 0, stream>>>(Wf, Wi, Wo, Wc, Wr);
    init_state<<<(Bb * Hh + 255) / 256, 256, 0, stream>>>(hbuf, cbuf);

    for (int t = 0; t < Tt; ++t) {
        const unsigned short* hin = hbuf + (size_t)(t & 1) * Bb * Hh;
        unsigned short*      hout = hbuf + (size_t)((t + 1) & 1) * Bb * Hh;
        lstm_step<<<256, 256, 0, stream>>>(X, Wr, bF, bI, bO, bC, hin, hout, cbuf, out, t);
    }
}